// Round 2
// baseline (104.856 us; speedup 1.0000x reference)
//
#include <hip/hip_runtime.h>
#include <math.h>

#define HID 512
#define IN_FEAT 342
#define OUTD 311
#define BATCH 256
#define KP0 352           // layer-0 padded K (11 chunks of 32)
#define MP2 320           // layer-2 padded M
#define XROW (IN_FEAT + 1)

typedef unsigned short u16;
typedef short bf16x8 __attribute__((ext_vector_type(8)));
typedef float f32x4 __attribute__((ext_vector_type(4)));

__device__ __forceinline__ u16 f2bf_rne(float v) {
    unsigned int x = __float_as_uint(v);
    unsigned int r = (x + 0x7fffu + ((x >> 16) & 1u)) >> 16;
    return (u16)r;
}
__device__ __forceinline__ float bf2f(u16 u) {
    return __uint_as_float(((unsigned int)u) << 16);
}

// split 8 f32 -> hi/lo bf16x8 (same numerics as the verified prep kernel)
__device__ __forceinline__ void split8(const float* __restrict__ src, bf16x8& hi, bf16x8& lo) {
#pragma unroll
    for (int j = 0; j < 8; j++) {
        u16 h = f2bf_rne(src[j]);
        hi[j] = (short)h;
        lo[j] = (short)f2bf_rne(src[j] - bf2f(h));
    }
}

// ======= self-contained fused layer =======
// out[b][o] = act( sum_s d_s(b) * ( sum_k W[s][o][k]*H[b][k] + bias[s][o] ) )
// W read as raw f32 [4][MW][KW]; hi/lo split done in-register per lane.
// H: MODE 0 = from x (f32, convert during LDS staging); MODE 1 = bf16 hi/lo global buffers.
// dcoef recomputed inline per MFMA thread from x[b][342].
// 16xNB tile/block; wave = (slice s = w&3, b-half t = w>>2); NB=32 -> 8 waves, NB=16 -> 4.
template<int KP, int KLDS, int NB, int FINAL, int MODE, int KW, int MW>
__global__ __launch_bounds__(NB * 16, (NB == 16 ? 2 : 1)) void layer_f32w(
    const float* __restrict__ W,
    const float* __restrict__ x,
    const u16* __restrict__ Hhi, const u16* __restrict__ Hlo,
    const float* __restrict__ bias, int Mb,
    u16* __restrict__ Ohi, u16* __restrict__ Olo, float* __restrict__ outp)
{
    constexpr int NTHR = NB * 16;
    union SharedU {
        u16 h[2][NB * KLDS];
        float acc[4][NB][17];
    };
    __shared__ SharedU sm;

    const int tid = (int)threadIdx.x;
    const int b0 = (int)blockIdx.x * NB;
    const int o0 = (int)blockIdx.y * 16;

    // ---- stage H tile (NB rows x KP, hi+lo) into LDS ----
    constexpr int CH = KP / 8;
    if constexpr (MODE == 0) {
        // from x (f32): convert to hi/lo bf16 while staging; pad k>=IN_FEAT with 0
        for (int idx = tid; idx < NB * CH; idx += NTHR) {
            int r = idx / CH, c = idx - r * CH;
            int k = c * 8;
            const float* xr = x + (size_t)(b0 + r) * XROW;
            float src[8];
#pragma unroll
            for (int j = 0; j < 8; j++) {
                int kk = k + j;
                src[j] = (kk < IN_FEAT) ? xr[kk] : 0.f;
            }
            bf16x8 hi, lo;
            split8(src, hi, lo);
            *reinterpret_cast<bf16x8*>(&sm.h[0][r * KLDS + k]) = hi;
            *reinterpret_cast<bf16x8*>(&sm.h[1][r * KLDS + k]) = lo;
        }
    } else {
        for (int idx = tid; idx < NB * CH; idx += NTHR) {
            int r = idx / CH, c = idx - r * CH;
            size_t g = (size_t)(b0 + r) * KP + c * 8;
            *reinterpret_cast<uint4*>(&sm.h[0][r * KLDS + c * 8]) =
                *reinterpret_cast<const uint4*>(Hhi + g);
            *reinterpret_cast<uint4*>(&sm.h[1][r * KLDS + c * 8]) =
                *reinterpret_cast<const uint4*>(Hlo + g);
        }
    }
    __syncthreads();

    const int lane = tid & 63;
    const int w = tid >> 6;
    const int s = w & 3;                      // slice
    const int t = w >> 2;                     // b-half (0 for NB=16)
    const int m = lane & 15;
    const int q = lane >> 4;

    const int orow = o0 + m;
    const bool vrow = (MW == HID) ? true : (orow < MW);
    const float* wr = W + ((size_t)s * MW + (vrow ? orow : 0)) * KW;
    const u16* hp = &sm.h[0][(t * 16 + m) * KLDS + q * 8];

    // ---- inline cubic blend coefficient d_s(b) for this thread's (b, s) ----
    const int brow = b0 + t * 16 + m;
    const float ps = 4.f * x[(size_t)brow * XROW + IN_FEAT];
    const float fl = floorf(ps);
    const float mu = ps - fl;
    const int i1 = ((int)fl) & 3;
    const int jj = (s - i1) & 3;              // 0:c1, 1:c2, 2:c3, 3:c0
    const float mu2 = mu * mu, mu3 = mu2 * mu;
    const float ds = (jj == 0) ? ( 1.5f * mu3 - 2.5f * mu2 + 1.0f)
                   : (jj == 1) ? (-1.5f * mu3 + 2.0f * mu2 + 0.5f * mu)
                   : (jj == 2) ? ( 0.5f * mu3 - 0.5f * mu2)
                   :             (-0.5f * mu3 + mu2 - 0.5f * mu);

    f32x4 a0 = {0.f, 0.f, 0.f, 0.f};
    f32x4 a1 = {0.f, 0.f, 0.f, 0.f};
    f32x4 a2 = {0.f, 0.f, 0.f, 0.f};
#pragma unroll
    for (int cc = 0; cc < KP / 32; ++cc) {
        const int k0 = cc * 32 + q * 8;
        float ws[8];
        if (vrow && (cc * 32 + 32 <= KW)) {   // chunk fully in-bounds for all q
            if constexpr (KW % 4 == 0) {
                const float4* p = reinterpret_cast<const float4*>(wr + k0);
                float4 v0 = p[0], v1 = p[1];
                ws[0] = v0.x; ws[1] = v0.y; ws[2] = v0.z; ws[3] = v0.w;
                ws[4] = v1.x; ws[5] = v1.y; ws[6] = v1.z; ws[7] = v1.w;
            } else {                           // KW=342: rows only 8B-aligned
                const float2* p = reinterpret_cast<const float2*>(wr + k0);
                float2 v0 = p[0], v1 = p[1], v2 = p[2], v3 = p[3];
                ws[0] = v0.x; ws[1] = v0.y; ws[2] = v1.x; ws[3] = v1.y;
                ws[4] = v2.x; ws[5] = v2.y; ws[6] = v3.x; ws[7] = v3.y;
            }
        } else {
#pragma unroll
            for (int j = 0; j < 8; j++) {
                int kk = k0 + j;
                ws[j] = (vrow && kk < KW) ? wr[kk] : 0.f;
            }
        }
        bf16x8 ah, al;
        split8(ws, ah, al);
        bf16x8 bh = *reinterpret_cast<const bf16x8*>(hp + cc * 32);
        bf16x8 bl = *reinterpret_cast<const bf16x8*>(hp + cc * 32 + NB * KLDS);
        a0 = __builtin_amdgcn_mfma_f32_16x16x32_bf16(ah, bh, a0, 0, 0, 0);
        a1 = __builtin_amdgcn_mfma_f32_16x16x32_bf16(ah, bl, a1, 0, 0, 0);
        a2 = __builtin_amdgcn_mfma_f32_16x16x32_bf16(al, bh, a2, 0, 0, 0);
    }
    __syncthreads();   // LDS H reads done; reuse union as blend buffer

    // wave-phase blend: d_s(b) * (sum + bias_s). C layout: col=lane&15 (b), row=q*4+r (o).
    f32x4 sum = a0 + a1 + a2;
#pragma unroll
    for (int r = 0; r < 4; ++r) {
        int o = o0 + q * 4 + r;
        float bb = (o < Mb) ? bias[(size_t)s * Mb + o] : 0.f;
        sm.acc[s][t * 16 + m][q * 4 + r] = ds * (sum[r] + bb);
    }
    __syncthreads();

    // reduce 4 slices, activate, store: thread -> (b_l = tid>>4, o_l = tid&15)
    const int b_l = tid >> 4;
    const int o_l = tid & 15;
    float vv = sm.acc[0][b_l][o_l] + sm.acc[1][b_l][o_l]
             + sm.acc[2][b_l][o_l] + sm.acc[3][b_l][o_l];
    const int o = o0 + o_l;
    const int b = b0 + b_l;
    if (!FINAL) {
        float e = (vv > 0.f) ? vv : expm1f(vv);
        u16 h = f2bf_rne(e);
        Ohi[(size_t)b * HID + o] = h;
        Olo[(size_t)b * HID + o] = f2bf_rne(e - bf2f(h));
    } else if (o < OUTD) {
        outp[(size_t)b * OUTD + o] = vv;
    }
}

extern "C" void kernel_launch(void* const* d_in, const int* in_sizes, int n_in,
                              void* d_out, int out_size, void* d_ws, size_t ws_size,
                              hipStream_t stream) {
    const float* x  = (const float*)d_in[0];
    const float* W0 = (const float*)d_in[1];
    const float* b0v = (const float*)d_in[2];
    const float* W1 = (const float*)d_in[3];
    const float* b1v = (const float*)d_in[4];
    const float* W2 = (const float*)d_in[5];
    const float* b2v = (const float*)d_in[6];
    float* out = (float*)d_out;

    char* pw = (char*)d_ws;
    auto alloc = [&](size_t bytes) { char* r = pw; pw += (bytes + 255) & ~(size_t)255; return r; };

    u16* hahi = (u16*)alloc((size_t)BATCH * HID * 2);
    u16* halo = (u16*)alloc((size_t)BATCH * HID * 2);
    u16* hbhi = (u16*)alloc((size_t)BATCH * HID * 2);
    u16* hblo = (u16*)alloc((size_t)BATCH * HID * 2);

    // L0: K=352 (KW=342), M=512, NB=32 -> grid (8,32), 512 thr, H from x
    layer_f32w<KP0, 360, 32, 0, 0, IN_FEAT, HID><<<dim3(BATCH / 32, HID / 16), 512, 0, stream>>>(
        W0, x, nullptr, nullptr, b0v, HID, hahi, halo, nullptr);

    // L1: K=512, M=512, NB=32 -> grid (8,32), 512 thr
    layer_f32w<HID, 520, 32, 0, 1, HID, HID><<<dim3(BATCH / 32, HID / 16), 512, 0, stream>>>(
        W1, x, hahi, halo, b1v, HID, hbhi, hblo, nullptr);

    // L2: K=512, M=311 (Mp=320), NB=16 -> grid (16,20), 256 thr
    layer_f32w<HID, 520, 16, 1, 1, HID, OUTD><<<dim3(BATCH / 16, MP2 / 16), 256, 0, stream>>>(
        W2, x, hbhi, hblo, b2v, OUTD, nullptr, nullptr, out);
}

// Round 3
// 103.645 us; speedup vs baseline: 1.0117x; 1.0117x over previous
//
#include <hip/hip_runtime.h>
#include <math.h>

#define HID 512
#define IN_FEAT 342
#define OUTD 311
#define BATCH 256
#define KP0 352           // layer-0 padded K (11 chunks of 32)
#define MP2 320           // layer-2 padded M
#define XROW (IN_FEAT + 1)

typedef unsigned short u16;
typedef short bf16x8 __attribute__((ext_vector_type(8)));
typedef float f32x4 __attribute__((ext_vector_type(4)));

__device__ __forceinline__ u16 f2bf_rne(float v) {
    unsigned int x = __float_as_uint(v);
    unsigned int r = (x + 0x7fffu + ((x >> 16) & 1u)) >> 16;
    return (u16)r;
}
__device__ __forceinline__ float bf2f(u16 u) {
    return __uint_as_float(((unsigned int)u) << 16);
}

// split 8 f32 -> hi/lo bf16x8 (same numerics as the verified prep kernel)
__device__ __forceinline__ void split8(const float* __restrict__ src, bf16x8& hi, bf16x8& lo) {
#pragma unroll
    for (int j = 0; j < 8; j++) {
        u16 h = f2bf_rne(src[j]);
        hi[j] = (short)h;
        lo[j] = (short)f2bf_rne(src[j] - bf2f(h));
    }
}

// ======= self-contained fused layer, XCD-aware 1D grid =======
// out[b][o] = act( sum_s d_s(b) * ( sum_k W[s][o][k]*H[b][k] + bias[s][o] ) )
// W read as raw f32 [4][MW][KW]; hi/lo split in-register per lane.
// H: MODE 0 = from x (f32, convert during LDS staging); MODE 1 = bf16 hi/lo buffers.
// dcoef recomputed inline per MFMA thread from x[b][342].
// Block decode: blk = (by&7) + 8*bx + 64*(by>>3)  ->  blk%8 == by%8, so all 8
// bx-duplicates of one weight-column tile land on ONE XCD (weights L2-resident,
// ~8x less HBM weight traffic vs the old (bx,by) 2D grid).
// NB=32: 8 waves, wave = (slice s=w&3, b-half t=w>>2); pairs (w,w+4) share slice.
template<int KP, int KLDS, int NB, int FINAL, int MODE, int KW, int MW, int NBY>
__global__ __launch_bounds__(NB * 16, 1) void layer_f32w(
    const float* __restrict__ W,
    const float* __restrict__ x,
    const u16* __restrict__ Hhi, const u16* __restrict__ Hlo,
    const float* __restrict__ bias, int Mb,
    u16* __restrict__ Ohi, u16* __restrict__ Olo, float* __restrict__ outp)
{
    constexpr int NTHR = NB * 16;
    union SharedU {
        u16 h[2][NB * KLDS];
        float acc[4][NB][17];
    };
    __shared__ SharedU sm;

    const int blk = (int)blockIdx.x;
    const int bx = (blk >> 3) & 7;
    const int by = (blk & 7) | ((blk >> 6) << 3);
    if (by >= NBY) return;                    // padded-grid early-out (L2: 192->160)

    const int tid = (int)threadIdx.x;
    const int b0 = bx * NB;
    const int o0 = by * 16;

    // ---- stage H tile (NB rows x KP, hi+lo) into LDS ----
    constexpr int CH = KP / 8;
    if constexpr (MODE == 0) {
        // from x (f32): convert to hi/lo bf16 while staging; pad k>=IN_FEAT with 0
        for (int idx = tid; idx < NB * CH; idx += NTHR) {
            int r = idx / CH, c = idx - r * CH;
            int k = c * 8;
            const float* xr = x + (size_t)(b0 + r) * XROW;
            float src[8];
#pragma unroll
            for (int j = 0; j < 8; j++) {
                int kk = k + j;
                src[j] = (kk < IN_FEAT) ? xr[kk] : 0.f;
            }
            bf16x8 hi, lo;
            split8(src, hi, lo);
            *reinterpret_cast<bf16x8*>(&sm.h[0][r * KLDS + k]) = hi;
            *reinterpret_cast<bf16x8*>(&sm.h[1][r * KLDS + k]) = lo;
        }
    } else {
        for (int idx = tid; idx < NB * CH; idx += NTHR) {
            int r = idx / CH, c = idx - r * CH;
            size_t g = (size_t)(b0 + r) * KP + c * 8;
            *reinterpret_cast<uint4*>(&sm.h[0][r * KLDS + c * 8]) =
                *reinterpret_cast<const uint4*>(Hhi + g);
            *reinterpret_cast<uint4*>(&sm.h[1][r * KLDS + c * 8]) =
                *reinterpret_cast<const uint4*>(Hlo + g);
        }
    }
    __syncthreads();

    const int lane = tid & 63;
    const int w = tid >> 6;
    const int s = w & 3;                      // slice
    const int t = w >> 2;                     // b-half
    const int m = lane & 15;
    const int q = lane >> 4;

    const int orow = o0 + m;
    const bool vrow = (MW == HID) ? true : (orow < MW);
    const float* wr = W + ((size_t)s * MW + (vrow ? orow : 0)) * KW;
    const u16* hp = &sm.h[0][(t * 16 + m) * KLDS + q * 8];

    // ---- inline cubic blend coefficient d_s(b) for this thread's (b, s) ----
    const int brow = b0 + t * 16 + m;
    const float ps = 4.f * x[(size_t)brow * XROW + IN_FEAT];
    const float fl = floorf(ps);
    const float mu = ps - fl;
    const int i1 = ((int)fl) & 3;
    const int jj = (s - i1) & 3;              // 0:c1, 1:c2, 2:c3, 3:c0
    const float mu2 = mu * mu, mu3 = mu2 * mu;
    const float ds = (jj == 0) ? ( 1.5f * mu3 - 2.5f * mu2 + 1.0f)
                   : (jj == 1) ? (-1.5f * mu3 + 2.0f * mu2 + 0.5f * mu)
                   : (jj == 2) ? ( 0.5f * mu3 - 0.5f * mu2)
                   :             (-0.5f * mu3 + mu2 - 0.5f * mu);

    f32x4 a0 = {0.f, 0.f, 0.f, 0.f};
    f32x4 a1 = {0.f, 0.f, 0.f, 0.f};
    f32x4 a2 = {0.f, 0.f, 0.f, 0.f};
#pragma unroll
    for (int cc = 0; cc < KP / 32; ++cc) {
        const int k0 = cc * 32 + q * 8;
        float ws[8];
        if (vrow && (cc * 32 + 32 <= KW)) {   // chunk fully in-bounds for all q
            if constexpr (KW % 4 == 0) {
                const float4* p = reinterpret_cast<const float4*>(wr + k0);
                float4 v0 = p[0], v1 = p[1];
                ws[0] = v0.x; ws[1] = v0.y; ws[2] = v0.z; ws[3] = v0.w;
                ws[4] = v1.x; ws[5] = v1.y; ws[6] = v1.z; ws[7] = v1.w;
            } else {                           // KW=342: rows only 8B-aligned
                const float2* p = reinterpret_cast<const float2*>(wr + k0);
                float2 v0 = p[0], v1 = p[1], v2 = p[2], v3 = p[3];
                ws[0] = v0.x; ws[1] = v0.y; ws[2] = v1.x; ws[3] = v1.y;
                ws[4] = v2.x; ws[5] = v2.y; ws[6] = v3.x; ws[7] = v3.y;
            }
        } else {
#pragma unroll
            for (int j = 0; j < 8; j++) {
                int kk = k0 + j;
                ws[j] = (vrow && kk < KW) ? wr[kk] : 0.f;
            }
        }
        bf16x8 ah, al;
        split8(ws, ah, al);
        bf16x8 bh = *reinterpret_cast<const bf16x8*>(hp + cc * 32);
        bf16x8 bl = *reinterpret_cast<const bf16x8*>(hp + cc * 32 + NB * KLDS);
        a0 = __builtin_amdgcn_mfma_f32_16x16x32_bf16(ah, bh, a0, 0, 0, 0);
        a1 = __builtin_amdgcn_mfma_f32_16x16x32_bf16(ah, bl, a1, 0, 0, 0);
        a2 = __builtin_amdgcn_mfma_f32_16x16x32_bf16(al, bh, a2, 0, 0, 0);
    }
    __syncthreads();   // LDS H reads done; reuse union as blend buffer

    // wave-phase blend: d_s(b) * (sum + bias_s). C layout: col=lane&15 (b), row=q*4+r (o).
    f32x4 sum = a0 + a1 + a2;
#pragma unroll
    for (int r = 0; r < 4; ++r) {
        int o = o0 + q * 4 + r;
        float bb = (o < Mb) ? bias[(size_t)s * Mb + o] : 0.f;
        sm.acc[s][t * 16 + m][q * 4 + r] = ds * (sum[r] + bb);
    }
    __syncthreads();

    // reduce 4 slices, activate, store: thread -> (b_l = tid>>4, o_l = tid&15)
    const int b_l = tid >> 4;
    const int o_l = tid & 15;
    float vv = sm.acc[0][b_l][o_l] + sm.acc[1][b_l][o_l]
             + sm.acc[2][b_l][o_l] + sm.acc[3][b_l][o_l];
    const int o = o0 + o_l;
    const int b = b0 + b_l;
    if (!FINAL) {
        float e = (vv > 0.f) ? vv : expm1f(vv);
        u16 h = f2bf_rne(e);
        Ohi[(size_t)b * HID + o] = h;
        Olo[(size_t)b * HID + o] = f2bf_rne(e - bf2f(h));
    } else if (o < OUTD) {
        outp[(size_t)b * OUTD + o] = vv;
    }
}

extern "C" void kernel_launch(void* const* d_in, const int* in_sizes, int n_in,
                              void* d_out, int out_size, void* d_ws, size_t ws_size,
                              hipStream_t stream) {
    const float* x  = (const float*)d_in[0];
    const float* W0 = (const float*)d_in[1];
    const float* b0v = (const float*)d_in[2];
    const float* W1 = (const float*)d_in[3];
    const float* b1v = (const float*)d_in[4];
    const float* W2 = (const float*)d_in[5];
    const float* b2v = (const float*)d_in[6];
    float* out = (float*)d_out;

    char* pw = (char*)d_ws;
    auto alloc = [&](size_t bytes) { char* r = pw; pw += (bytes + 255) & ~(size_t)255; return r; };

    u16* hahi = (u16*)alloc((size_t)BATCH * HID * 2);
    u16* halo = (u16*)alloc((size_t)BATCH * HID * 2);
    u16* hbhi = (u16*)alloc((size_t)BATCH * HID * 2);
    u16* hblo = (u16*)alloc((size_t)BATCH * HID * 2);

    // L0: K=352 (KW=342), M=512 (NBY=32) -> 256 blocks, 512 thr, H from x
    layer_f32w<KP0, 360, 32, 0, 0, IN_FEAT, HID, 32><<<256, 512, 0, stream>>>(
        W0, x, nullptr, nullptr, b0v, HID, hahi, halo, nullptr);

    // L1: K=512, M=512 (NBY=32) -> 256 blocks, 512 thr
    layer_f32w<HID, 520, 32, 0, 1, HID, HID, 32><<<256, 512, 0, stream>>>(
        W1, x, hahi, halo, b1v, HID, hbhi, hblo, nullptr);

    // L2: K=512, M=311 (Mp=320, NBY=20) -> 192-block padded grid (160 active)
    layer_f32w<HID, 520, 32, 1, 1, HID, OUTD, 20><<<192, 512, 0, stream>>>(
        W2, x, hbhi, hblo, b2v, OUTD, nullptr, nullptr, out);
}